// Round 11
// baseline (1450.065 us; speedup 1.0000x reference)
//
#include <hip/hip_runtime.h>
#include <hip/hip_cooperative_groups.h>
#include <cstdint>

namespace cg = cooperative_groups;

constexpr int NG = 64;     // graphs
constexpr int H  = 256;    // hidden width

typedef __bf16 bf16x8 __attribute__((ext_vector_type(8)));
typedef float  f32x4  __attribute__((ext_vector_type(4)));

__device__ __forceinline__ uint32_t pk_bf16(float a, float b) {
    uint32_t ua = __builtin_bit_cast(uint32_t, a);
    uint32_t ub = __builtin_bit_cast(uint32_t, b);
    ua += 0x7fffu + ((ua >> 16) & 1u);
    ub += 0x7fffu + ((ub >> 16) & 1u);
    return (ua >> 16) | (ub & 0xffff0000u);
}
__device__ __forceinline__ ushort bf16r(float x) {
    uint32_t u = __builtin_bit_cast(uint32_t, x);
    u += 0x7fffu + ((u >> 16) & 1u);
    return (ushort)(u >> 16);
}
__device__ __forceinline__ float bf2f(ushort h) {
    return __builtin_bit_cast(float, ((uint32_t)h) << 16);
}
__device__ __forceinline__ void bf2acc(uint32_t u, float& a0, float& a1) {
    a0 += __builtin_bit_cast(float, u << 16);
    a1 += __builtin_bit_cast(float, u & 0xffff0000u);
}

struct Params {
    const float* x; const int* ei; const int* bat;
    const float* w1; const float* b1; const float* w2; const float* b2;
    const float* w3; const float* b3;
    const float* l1w; const float* l1b; const float* l2w; const float* l2b;
    float* out;
    int N, E, NB;
    int* cnt; float* dinv; int* row_ptr; int* fill;
    ushort* ssrc; int* bsum; int* boff;
    ushort* yb; ushort* z16;
    ushort* wt1h; ushort* wt1l; ushort* wt2h; ushort* wt2l;
};

union SMem {
    int scan[256];
    struct { ushort As[64][72]; ushort Bh[64][72]; ushort Bl[64][72]; } g;   // 27.6 KB
    struct { float pooled[256]; float t3[256]; float mid[128]; } h;
};

__device__ __forceinline__ int lower_bound(const int* a, int n, int v) {
    int lo = 0, hi = n;
    while (lo < hi) { int m = (lo + hi) >> 1; if (a[m] < v) lo = m + 1; else hi = m; }
    return lo;
}

// ---- chunked agg phase (r10 v3 structure): wave = 8 nodes x 1 chunk ----
template<int NC>
__device__ void agg_phase(const Params& p, const ushort* __restrict__ y,
                          ushort* __restrict__ z) {
    int wave = threadIdx.x >> 6, lane = threadIdx.x & 63;
    int grp = lane >> 3, fd = lane & 7;
    int nvb = ((p.N + 31) / 32) * NC;
    for (int vb = blockIdx.x; vb < nvb; vb += gridDim.x) {   // gridDim%8==0 -> chunk const/block
        int chunk = vb % NC;
        int node = (vb / NC) * 32 + wave * 8 + grp;
        if (node >= p.N) continue;
        const ushort* yc = y + (size_t)chunk * p.N * 32;
        float a0 = 0.f, a1 = 0.f, a2 = 0.f, a3 = 0.f;
        {
            uint2 u = *reinterpret_cast<const uint2*>(yc + (size_t)node * 32 + fd * 4);
            bf2acc(u.x, a0, a1); bf2acc(u.y, a2, a3);
        }
        int beg = p.row_ptr[node], end = p.row_ptr[node + 1];
        int e = beg;
        for (; e + 2 <= end; e += 2) {
            int s0 = p.ssrc[e], s1 = p.ssrc[e + 1];
            uint2 u0 = *reinterpret_cast<const uint2*>(yc + (size_t)s0 * 32 + fd * 4);
            uint2 u1 = *reinterpret_cast<const uint2*>(yc + (size_t)s1 * 32 + fd * 4);
            bf2acc(u0.x, a0, a1); bf2acc(u0.y, a2, a3);
            bf2acc(u1.x, a0, a1); bf2acc(u1.y, a2, a3);
        }
        if (e < end) {
            int s = p.ssrc[e];
            uint2 u = *reinterpret_cast<const uint2*>(yc + (size_t)s * 32 + fd * 4);
            bf2acc(u.x, a0, a1); bf2acc(u.y, a2, a3);
        }
        float dv = p.dinv[node];
        uint2 o;
        o.x = pk_bf16(dv * a0, dv * a1);
        o.y = pk_bf16(dv * a2, dv * a3);
        *reinterpret_cast<uint2*>(z + ((size_t)chunk * p.N + node) * 32 + fd * 4) = o;
    }
}

// ---- MFMA GEMM phase, BM=64 tiles (r6-proven layout), chunk-major A/C ----
__device__ void gemm_phase(const Params& p, SMem& sm, const ushort* __restrict__ A,
                           const ushort* __restrict__ Bhi, const ushort* __restrict__ Blo,
                           const float* __restrict__ bias, ushort* __restrict__ C, int K) {
    const int tid = threadIdx.x;
    const int w = tid >> 6, l = tid & 63, lr = l & 15, lk = (l >> 4) * 8;
    const int M = p.N;
    int ntile = ((M + 63) / 64) * 4;
    for (int vt = blockIdx.x; vt < ntile; vt += gridDim.x) {
        int bm = (vt >> 2) * 64;
        int bn = (vt & 3) * 64;
        f32x4 acc[4];
        #pragma unroll
        for (int i = 0; i < 4; ++i) acc[i] = (f32x4){0.f, 0.f, 0.f, 0.f};
        for (int k0 = 0; k0 < K; k0 += 64) {
            #pragma unroll
            for (int pass = 0; pass < 2; ++pass) {   // 512 slots x 8 bf16 per tile array
                int g = tid + pass * 256;
                int r = g >> 3, c = (g & 7) << 3;
                int grow = bm + r, gk = k0 + c;
                uint4 va = make_uint4(0u, 0u, 0u, 0u);
                if (grow < M)
                    va = *reinterpret_cast<const uint4*>(A + ((size_t)(gk >> 5) * M + grow) * 32 + (gk & 31));
                *reinterpret_cast<uint4*>(&sm.g.As[r][c]) = va;
                *reinterpret_cast<uint4*>(&sm.g.Bh[r][c]) =
                    *reinterpret_cast<const uint4*>(Bhi + (size_t)(bn + r) * K + k0 + c);
                *reinterpret_cast<uint4*>(&sm.g.Bl[r][c]) =
                    *reinterpret_cast<const uint4*>(Blo + (size_t)(bn + r) * K + k0 + c);
            }
            __syncthreads();
            #pragma unroll
            for (int kk = 0; kk < 64; kk += 32) {
                bf16x8 bh = *reinterpret_cast<const bf16x8*>(&sm.g.Bh[w * 16 + lr][kk + lk]);
                bf16x8 bl = *reinterpret_cast<const bf16x8*>(&sm.g.Bl[w * 16 + lr][kk + lk]);
                #pragma unroll
                for (int r16 = 0; r16 < 4; ++r16) {
                    bf16x8 a = *reinterpret_cast<const bf16x8*>(&sm.g.As[r16 * 16 + lr][kk + lk]);
                    acc[r16] = __builtin_amdgcn_mfma_f32_16x16x32_bf16(a, bh, acc[r16], 0, 0, 0);
                    acc[r16] = __builtin_amdgcn_mfma_f32_16x16x32_bf16(a, bl, acc[r16], 0, 0, 0);
                }
            }
            __syncthreads();
        }
        int col = bn + w * 16 + lr;
        int cc = col >> 5, co = col & 31;
        float bv = bias[col];
        #pragma unroll
        for (int r16 = 0; r16 < 4; ++r16) {
            #pragma unroll
            for (int j = 0; j < 4; ++j) {
                int row = bm + r16 * 16 + (l >> 4) * 4 + j;
                if (row < M) {
                    float v = acc[r16][j] + bv;
                    v = fmaxf(v, 0.f);
                    v *= p.dinv[row];
                    C[((size_t)cc * M + row) * 32 + co] = bf16r(v);
                }
            }
        }
    }
}

constexpr int WCONV_TOT = (128 + 256) * 256;   // both weight matrices

__global__ __launch_bounds__(256, 4) void mega(Params p) {
    cg::grid_group grid = cg::this_grid();
    __shared__ SMem sm;
    const int tid = threadIdx.x;
    const int gstride = gridDim.x * 256;
    const int gthread = blockIdx.x * 256 + tid;

    // P0: zero cnt
    for (int i = gthread; i < p.N; i += gstride) p.cnt[i] = 0;
    grid.sync();

    // P1: degree histogram + wconv (independent)
    for (int e = gthread; e < p.E; e += gstride) atomicAdd(&p.cnt[p.ei[p.E + e]], 1);
    for (int idx0 = gthread; idx0 < WCONV_TOT; idx0 += gstride) {
        int idx = idx0;
        const float* w; ushort *hi, *lo; int K;
        if (idx < 128 * 256) { w = p.w1; hi = p.wt1h; lo = p.wt1l; K = 128; }
        else { idx -= 128 * 256; w = p.w2; hi = p.wt2h; lo = p.wt2l; K = 256; }
        int k = idx / 256, n = idx & 255;
        float v = w[idx];
        ushort h = bf16r(v);
        hi[n * K + k] = h;
        lo[n * K + k] = bf16r(v - bf2f(h));
    }
    grid.sync();

    // P2: scanA (block sums) + dinv
    for (int vb = blockIdx.x; vb < p.NB; vb += gridDim.x) {
        int i = vb * 256 + tid;
        int v = (i < p.N) ? p.cnt[i] : 0;
        if (i < p.N) p.dinv[i] = rsqrtf((float)(v + 1));
        sm.scan[tid] = v;
        __syncthreads();
        for (int off = 128; off > 0; off >>= 1) {
            if (tid < off) sm.scan[tid] += sm.scan[tid + off];
            __syncthreads();
        }
        if (tid == 0) p.bsum[vb] = sm.scan[0];
        __syncthreads();
    }
    grid.sync();

    // P3: scanB (block 0 only); also writes row_ptr[N] = E total
    if (blockIdx.x == 0) {
        int v = (tid < p.NB) ? p.bsum[tid] : 0;
        sm.scan[tid] = v;
        __syncthreads();
        for (int off = 1; off < 256; off <<= 1) {
            int a = (tid >= off) ? sm.scan[tid - off] : 0;
            __syncthreads();
            sm.scan[tid] += a;
            __syncthreads();
        }
        if (tid < p.NB) p.boff[tid] = sm.scan[tid] - v;
        if (tid == p.NB - 1) p.row_ptr[p.N] = sm.scan[tid];
    }
    grid.sync();

    // P4: scanC (per-node exclusive offsets)
    for (int vb = blockIdx.x; vb < p.NB; vb += gridDim.x) {
        int i = vb * 256 + tid;
        int v = (i < p.N) ? p.cnt[i] : 0;
        sm.scan[tid] = v;
        __syncthreads();
        for (int off = 1; off < 256; off <<= 1) {
            int a = (tid >= off) ? sm.scan[tid - off] : 0;
            __syncthreads();
            sm.scan[tid] += a;
            __syncthreads();
        }
        if (i < p.N) {
            int excl = p.boff[vb] + sm.scan[tid] - v;
            p.row_ptr[i] = excl;
            p.fill[i] = excl;
        }
        __syncthreads();
    }
    grid.sync();

    // P5: counting-sort scatter + prescale y0 = bf16(dinv*x), chunk-major [4][N][32]
    for (int i = gthread; i < p.E; i += gstride) {
        int pos = atomicAdd(&p.fill[p.ei[p.E + i]], 1);
        p.ssrc[pos] = (ushort)p.ei[i];
    }
    for (int i = gthread; i < p.N * 32; i += gstride) {
        int f = i * 4;
        int node = f >> 7;
        int k = f & 127;
        float dv = p.dinv[node];
        float4 v = *reinterpret_cast<const float4*>(p.x + f);
        uint2 o;
        o.x = pk_bf16(v.x * dv, v.y * dv);
        o.y = pk_bf16(v.z * dv, v.w * dv);
        *reinterpret_cast<uint2*>(p.yb + ((size_t)(k >> 5) * p.N + node) * 32 + (k & 31)) = o;
    }
    grid.sync();

    // P6..P10: layer1 agg -> gemm1 -> layer2 agg -> gemm2 -> layer3 agg
    agg_phase<4>(p, p.yb, p.z16);
    grid.sync();
    gemm_phase(p, sm, p.z16, p.wt1h, p.wt1l, p.b1, p.yb, 128);
    grid.sync();
    agg_phase<8>(p, p.yb, p.z16);
    grid.sync();
    gemm_phase(p, sm, p.z16, p.wt2h, p.wt2l, p.b2, p.yb, 256);
    grid.sync();
    agg_phase<8>(p, p.yb, p.z16);
    grid.sync();

    // P11: pool (binary-search graph range, no atomics) + head, blocks 0..63
    if (blockIdx.x < NG) {
        int g = blockIdx.x;
        int lo = lower_bound(p.bat, p.N, g);
        int hi = lower_bound(p.bat, p.N, g + 1);
        size_t poff = (size_t)(tid >> 5) * p.N;
        int co = tid & 31;
        float s = 0.f;
        for (int i = lo; i < hi; ++i) s += bf2f(p.z16[(poff + i) * 32 + co]);
        sm.h.pooled[tid] = s / (float)max(hi - lo, 1);
        __syncthreads();
        float a = p.b3[tid];
        for (int k = 0; k < H; ++k) a += sm.h.pooled[k] * p.w3[k * H + tid];
        sm.h.t3[tid] = a;
        __syncthreads();
        if (tid < H / 2) {
            float m = p.l1b[tid];
            for (int k = 0; k < H; ++k) m += sm.h.t3[k] * p.l1w[k * (H / 2) + tid];
            sm.h.mid[tid] = m;
        }
        __syncthreads();
        if (tid < 3) {
            float o = p.l2b[tid];
            for (int k = 0; k < H / 2; ++k) o += sm.h.mid[k] * p.l2w[k * 3 + tid];
            p.out[g * 3 + tid] = o;
        }
    }
}

extern "C" void kernel_launch(void* const* d_in, const int* in_sizes, int n_in,
                              void* d_out, int out_size, void* d_ws, size_t ws_size,
                              hipStream_t stream) {
    Params P;
    P.x   = (const float*)d_in[0];
    P.ei  = (const int*)d_in[2];
    P.bat = (const int*)d_in[3];
    P.w1  = (const float*)d_in[4];  P.b1 = (const float*)d_in[5];
    P.w2  = (const float*)d_in[6];  P.b2 = (const float*)d_in[7];
    P.w3  = (const float*)d_in[8];  P.b3 = (const float*)d_in[9];
    P.l1w = (const float*)d_in[10]; P.l1b = (const float*)d_in[11];
    P.l2w = (const float*)d_in[12]; P.l2b = (const float*)d_in[13];
    P.out = (float*)d_out;
    P.N = in_sizes[0] / 128;       // 50000
    P.E = in_sizes[2] / 2;         // 800000
    P.NB = (P.N + 255) / 256;

    char* ws = (char*)d_ws;
    size_t off = 0;
    auto alloc = [&](size_t bytes) {
        void* ptr = ws + off;
        off = (off + bytes + 255) & ~(size_t)255;
        return ptr;
    };
    P.yb      = (ushort*)alloc((size_t)P.N * H * 2);
    P.z16     = (ushort*)alloc((size_t)P.N * H * 2);
    P.cnt     = (int*)alloc((size_t)P.N * 4);
    P.dinv    = (float*)alloc((size_t)P.N * 4);
    P.row_ptr = (int*)alloc((size_t)(P.N + 1) * 4);
    P.fill    = (int*)alloc((size_t)P.N * 4);
    P.ssrc    = (ushort*)alloc((size_t)P.E * 2);
    P.bsum    = (int*)alloc(256 * 4);
    P.boff    = (int*)alloc(256 * 4);
    P.wt1h    = (ushort*)alloc((size_t)128 * 256 * 2);
    P.wt1l    = (ushort*)alloc((size_t)128 * 256 * 2);
    P.wt2h    = (ushort*)alloc((size_t)256 * 256 * 2);
    P.wt2l    = (ushort*)alloc((size_t)256 * 256 * 2);

    int blocksPerCU = 0;
    hipOccupancyMaxActiveBlocksPerMultiprocessor(&blocksPerCU, mega, 256, 0);
    int numCU = 0, dev = 0;
    hipGetDevice(&dev);
    hipDeviceGetAttribute(&numCU, hipDeviceAttributeMultiprocessorCount, dev);
    int grid = blocksPerCU * numCU;
    if (grid <= 0) grid = 1024;
    grid &= ~7;                       // multiple of 8 keeps chunk->XCD affinity under grid-stride
    if (grid < 64) grid = 64;

    void* args[] = { &P };
    hipLaunchCooperativeKernel(mega, dim3(grid), dim3(256), args, 0, stream);
}

// Round 12
// 615.068 us; speedup vs baseline: 2.3576x; 2.3576x over previous
//
#include <hip/hip_runtime.h>
#include <cstdint>

constexpr int NG = 64;     // graphs
constexpr int H  = 256;    // hidden width

typedef __bf16 bf16x8 __attribute__((ext_vector_type(8)));
typedef float  f32x4  __attribute__((ext_vector_type(4)));

__device__ __forceinline__ uint32_t pk_bf16(float a, float b) {
    uint32_t ua = __builtin_bit_cast(uint32_t, a);
    uint32_t ub = __builtin_bit_cast(uint32_t, b);
    ua += 0x7fffu + ((ua >> 16) & 1u);
    ub += 0x7fffu + ((ub >> 16) & 1u);
    return (ua >> 16) | (ub & 0xffff0000u);
}
__device__ __forceinline__ ushort bf16r(float x) {
    uint32_t u = __builtin_bit_cast(uint32_t, x);
    u += 0x7fffu + ((u >> 16) & 1u);
    return (ushort)(u >> 16);
}
__device__ __forceinline__ float bf2f(ushort h) {
    return __builtin_bit_cast(float, ((uint32_t)h) << 16);
}
__device__ __forceinline__ void bf2acc(uint32_t u, float& a0, float& a1) {
    a0 += __builtin_bit_cast(float, u << 16);
    a1 += __builtin_bit_cast(float, u & 0xffff0000u);
}
__device__ __forceinline__ int lower_bound(const int* a, int n, int v) {
    int lo = 0, hi = n;
    while (lo < hi) { int m = (lo + hi) >> 1; if (a[m] < v) lo = m + 1; else hi = m; }
    return lo;
}

// ---------- degree histogram ----------
__global__ void hist_kernel(const int* __restrict__ dst, int* __restrict__ cnt, int E) {
    int e = blockIdx.x * blockDim.x + threadIdx.x;
    if (e < E) atomicAdd(&cnt[dst[e]], 1);
}

// ---------- scanA + dinv + zero c ----------
__global__ __launch_bounds__(256) void scanA(const int* __restrict__ cnt, int* __restrict__ bsum,
                                             float* __restrict__ dinv, float* __restrict__ c, int n) {
    __shared__ int sh[256];
    int t = threadIdx.x, i = blockIdx.x * 256 + t;
    int v = (i < n) ? cnt[i] : 0;
    if (i < n) {
        dinv[i] = rsqrtf((float)(v + 1));
        float4 z4 = make_float4(0.f, 0.f, 0.f, 0.f);
        float4* cp = reinterpret_cast<float4*>(c + (size_t)i * NG);
        #pragma unroll
        for (int q = 0; q < NG / 4; ++q) cp[q] = z4;
    }
    sh[t] = v;
    __syncthreads();
    for (int off = 128; off > 0; off >>= 1) {
        if (t < off) sh[t] += sh[t + off];
        __syncthreads();
    }
    if (t == 0) bsum[blockIdx.x] = sh[0];
}

// ---------- scanB + zero sums ----------
__global__ __launch_bounds__(256) void scanB(const int* __restrict__ bsum, int* __restrict__ boff,
                                             int* __restrict__ total_out, int nb,
                                             float* __restrict__ sums) {
    __shared__ int sh[256];
    int t = threadIdx.x;
    for (int i = t; i < NG * H; i += 256) sums[i] = 0.f;
    int v = (t < nb) ? bsum[t] : 0;
    sh[t] = v;
    __syncthreads();
    for (int off = 1; off < 256; off <<= 1) {
        int a = (t >= off) ? sh[t - off] : 0;
        __syncthreads();
        sh[t] += a;
        __syncthreads();
    }
    if (t < nb) boff[t] = sh[t] - v;
    if (t == nb - 1) *total_out = sh[t];
}

__global__ __launch_bounds__(256) void scanC(const int* __restrict__ cnt, const int* __restrict__ boff,
                                             int* __restrict__ row_ptr, int* __restrict__ fill, int n) {
    __shared__ int sh[256];
    int t = threadIdx.x, i = blockIdx.x * 256 + t;
    int v = (i < n) ? cnt[i] : 0;
    sh[t] = v;
    __syncthreads();
    for (int off = 1; off < 256; off <<= 1) {
        int a = (t >= off) ? sh[t - off] : 0;
        __syncthreads();
        sh[t] += a;
        __syncthreads();
    }
    if (i < n) {
        int excl = boff[blockIdx.x] + sh[t] - v;
        row_ptr[i] = excl;
        fill[i] = excl;
    }
}

// ---------- fused: wconv + scatter + c-matrix edges + prescale ----------
// y layout: chunk-major [4][N][32] bf16 (width 128); c[j][g] += dinv[d] per edge (j->d)
constexpr int WCONV_BLOCKS = (128 * 256 + 256 * 256) / 256;   // 384
__global__ void wsp_kernel(const float* __restrict__ w1, ushort* __restrict__ h1, ushort* __restrict__ l1,
                           const float* __restrict__ w2, ushort* __restrict__ h2, ushort* __restrict__ l2,
                           const int* __restrict__ src, const int* __restrict__ dst,
                           int* __restrict__ fill, ushort* __restrict__ ssrc, int E,
                           const float* __restrict__ x, const float* __restrict__ dinv,
                           const int* __restrict__ bat, float* __restrict__ c,
                           ushort* __restrict__ y, int N) {
    if (blockIdx.x < WCONV_BLOCKS) {
        int idx = blockIdx.x * 256 + threadIdx.x;
        const float* w; ushort *hi, *lo; int K;
        if (idx < 128 * 256) { w = w1; hi = h1; lo = l1; K = 128; }
        else { idx -= 128 * 256; w = w2; hi = h2; lo = l2; K = 256; }
        int k = idx / 256, n = idx & 255;
        float v = w[idx];
        ushort h = bf16r(v);
        hi[n * K + k] = h;
        lo[n * K + k] = bf16r(v - bf2f(h));
        return;
    }
    int i = (blockIdx.x - WCONV_BLOCKS) * 256 + threadIdx.x;
    if (i < E) {
        int s = src[i], d = dst[i];
        int pos = atomicAdd(&fill[d], 1);
        ssrc[pos] = (ushort)s;
        atomicAdd(&c[(size_t)s * NG + bat[d]], dinv[d]);   // pool-coefficient edge term
    }
    if (i < N) {
        atomicAdd(&c[(size_t)i * NG + bat[i]], dinv[i]);   // self-loop term
    }
    int np4 = N * 32;   // N*128/4
    if (i < np4) {
        int f = i * 4;
        int node = f >> 7;
        int k = f & 127;
        float dv = dinv[node];
        float4 v = *reinterpret_cast<const float4*>(x + f);
        uint2 o;
        o.x = pk_bf16(v.x * dv, v.y * dv);
        o.y = pk_bf16(v.z * dv, v.w * dv);
        *reinterpret_cast<uint2*>(y + ((size_t)(k >> 5) * N + node) * 32 + (k & 31)) = o;
    }
}

// ---------- chunked agg v3 + unroll4: wave = 8 nodes x 1 chunk ----------
template<int NC>
__global__ __launch_bounds__(256) void agg_kernel(const ushort* __restrict__ y,
                                                  const float* __restrict__ dinv,
                                                  const int* __restrict__ row_ptr,
                                                  const ushort* __restrict__ ssrc,
                                                  ushort* __restrict__ zout, int n) {
    int wave = threadIdx.x >> 6;
    int lane = threadIdx.x & 63;
    int grp  = lane >> 3;
    int fd   = lane & 7;
    int chunk = blockIdx.x % NC;
    int node  = (blockIdx.x / NC) * 32 + wave * 8 + grp;
    if (node >= n) return;
    const ushort* yc = y + (size_t)chunk * n * 32;

    float a0, a1, a2, a3;
    {   // self term
        uint2 u = *reinterpret_cast<const uint2*>(yc + (size_t)node * 32 + fd * 4);
        a0 = a1 = a2 = a3 = 0.f;
        bf2acc(u.x, a0, a1); bf2acc(u.y, a2, a3);
    }
    int beg = row_ptr[node], end = row_ptr[node + 1];
    int e = beg;
    for (; e + 4 <= end; e += 4) {     // 4 independent gathers in flight per group
        int s0 = ssrc[e], s1 = ssrc[e + 1], s2 = ssrc[e + 2], s3 = ssrc[e + 3];
        uint2 u0 = *reinterpret_cast<const uint2*>(yc + (size_t)s0 * 32 + fd * 4);
        uint2 u1 = *reinterpret_cast<const uint2*>(yc + (size_t)s1 * 32 + fd * 4);
        uint2 u2 = *reinterpret_cast<const uint2*>(yc + (size_t)s2 * 32 + fd * 4);
        uint2 u3 = *reinterpret_cast<const uint2*>(yc + (size_t)s3 * 32 + fd * 4);
        bf2acc(u0.x, a0, a1); bf2acc(u0.y, a2, a3);
        bf2acc(u1.x, a0, a1); bf2acc(u1.y, a2, a3);
        bf2acc(u2.x, a0, a1); bf2acc(u2.y, a2, a3);
        bf2acc(u3.x, a0, a1); bf2acc(u3.y, a2, a3);
    }
    for (; e < end; ++e) {
        int s = ssrc[e];
        uint2 u = *reinterpret_cast<const uint2*>(yc + (size_t)s * 32 + fd * 4);
        bf2acc(u.x, a0, a1); bf2acc(u.y, a2, a3);
    }
    float dv = dinv[node];
    uint2 o;
    o.x = pk_bf16(dv * a0, dv * a1);
    o.y = pk_bf16(dv * a2, dv * a3);
    *reinterpret_cast<uint2*>(zout + ((size_t)chunk * n + node) * 32 + fd * 4) = o;
}

// ---------- MFMA GEMM: chunk-major A [K/32][M][32], C [256/32][M][32] ----------
template<bool RELU>
__global__ __launch_bounds__(256) void mfma_gemm(const ushort* __restrict__ A,
                                                 const ushort* __restrict__ Bhi,
                                                 const ushort* __restrict__ Blo,
                                                 const float* __restrict__ bias,
                                                 const float* __restrict__ dinv,
                                                 ushort* __restrict__ C, int M, int K) {
    constexpr int BM = 128, BN = 64, BK = 64;
    constexpr int LDK = BK + 8;
    __shared__ ushort As[BM][LDK];
    __shared__ ushort Bh[BN][LDK];
    __shared__ ushort Bl[BN][LDK];

    const int tid = threadIdx.x;
    const int w = tid >> 6;
    const int l = tid & 63;
    const int lr = l & 15;
    const int lk = (l >> 4) * 8;
    const int bm = blockIdx.x * BM;
    const int bn = blockIdx.y * BN;

    f32x4 acc[8];
    #pragma unroll
    for (int i = 0; i < 8; ++i) acc[i] = (f32x4){0.f, 0.f, 0.f, 0.f};

    for (int k0 = 0; k0 < K; k0 += BK) {
        #pragma unroll
        for (int p = 0; p < 4; ++p) {
            int g = tid + p * 256;
            int r = g >> 3;
            int c = (g & 7) << 3;
            int grow = bm + r;
            int gk = k0 + c;
            uint4 va = make_uint4(0u, 0u, 0u, 0u);
            if (grow < M)
                va = *reinterpret_cast<const uint4*>(A + ((size_t)(gk >> 5) * M + grow) * 32 + (gk & 31));
            *reinterpret_cast<uint4*>(&As[r][c]) = va;
        }
        #pragma unroll
        for (int p = 0; p < 2; ++p) {
            int g = tid + p * 256;
            int r = g >> 3;
            int c = (g & 7) << 3;
            *reinterpret_cast<uint4*>(&Bh[r][c]) =
                *reinterpret_cast<const uint4*>(Bhi + (size_t)(bn + r) * K + k0 + c);
            *reinterpret_cast<uint4*>(&Bl[r][c]) =
                *reinterpret_cast<const uint4*>(Blo + (size_t)(bn + r) * K + k0 + c);
        }
        __syncthreads();
        #pragma unroll
        for (int kk = 0; kk < BK; kk += 32) {
            bf16x8 bh = *reinterpret_cast<const bf16x8*>(&Bh[w * 16 + lr][kk + lk]);
            bf16x8 bl = *reinterpret_cast<const bf16x8*>(&Bl[w * 16 + lr][kk + lk]);
            #pragma unroll
            for (int r16 = 0; r16 < 8; ++r16) {
                bf16x8 a = *reinterpret_cast<const bf16x8*>(&As[r16 * 16 + lr][kk + lk]);
                acc[r16] = __builtin_amdgcn_mfma_f32_16x16x32_bf16(a, bh, acc[r16], 0, 0, 0);
                acc[r16] = __builtin_amdgcn_mfma_f32_16x16x32_bf16(a, bl, acc[r16], 0, 0, 0);
            }
        }
        __syncthreads();
    }

    int col = bn + w * 16 + lr;
    int cc = col >> 5, co = col & 31;
    float bv = bias[col];
    #pragma unroll
    for (int r16 = 0; r16 < 8; ++r16) {
        #pragma unroll
        for (int j = 0; j < 4; ++j) {
            int row = bm + r16 * 16 + (l >> 4) * 4 + j;
            if (row < M) {
                float v = acc[r16][j] + bv;
                if (RELU) v = fmaxf(v, 0.f);
                v *= dinv[row];
                C[((size_t)cc * M + row) * 32 + co] = bf16r(v);
            }
        }
    }
}

// ---------- pool-GEMM: sums[g][f] = sum_j c[j][g] * y[chunk(f)][j][co(f)] ----------
// block = (chunk, node-tile of TN); thread t: g = t>>2, 16B quad q = t&3
__global__ __launch_bounds__(256) void pg_kernel(const ushort* __restrict__ y,
                                                 const float* __restrict__ c,
                                                 float* __restrict__ sums, int n) {
    constexpr int TN = 512;
    int chunk = blockIdx.x & 7;
    int base  = (blockIdx.x >> 3) * TN;
    if (base >= n) return;
    int endn = min(base + TN, n);
    int t = threadIdx.x;
    int g = t >> 2;
    int q = t & 3;
    const ushort* yp = y + (size_t)chunk * n * 32;
    float acc[8] = {};
    for (int i = base; i < endn; ++i) {
        float cv = c[(size_t)i * NG + g];
        uint4 u = *reinterpret_cast<const uint4*>(yp + (size_t)i * 32 + q * 8);
        float f0, f1, f2, f3, f4, f5, f6, f7;
        f0 = f1 = f2 = f3 = f4 = f5 = f6 = f7 = 0.f;
        bf2acc(u.x, f0, f1); bf2acc(u.y, f2, f3);
        bf2acc(u.z, f4, f5); bf2acc(u.w, f6, f7);
        acc[0] += cv * f0; acc[1] += cv * f1; acc[2] += cv * f2; acc[3] += cv * f3;
        acc[4] += cv * f4; acc[5] += cv * f5; acc[6] += cv * f6; acc[7] += cv * f7;
    }
    float* sp = sums + g * H + chunk * 32 + q * 8;
    #pragma unroll
    for (int k = 0; k < 8; ++k) atomicAdd(&sp[k], acc[k]);
}

// ---------- head: counts via binary search on sorted batch ----------
__global__ __launch_bounds__(256) void head_kernel(const float* __restrict__ sums,
                                                   const int* __restrict__ bat, int n,
                                                   const float* __restrict__ w3, const float* __restrict__ b3,
                                                   const float* __restrict__ l1w, const float* __restrict__ l1b,
                                                   const float* __restrict__ l2w, const float* __restrict__ l2b,
                                                   float* __restrict__ out) {
    __shared__ float pooled[H];
    __shared__ float t3[H];
    __shared__ float mid[H / 2];
    int g = blockIdx.x, t = threadIdx.x;
    int lo = lower_bound(bat, n, g);
    int hi = lower_bound(bat, n, g + 1);
    float cdeg = (float)max(hi - lo, 1);
    pooled[t] = sums[g * H + t] / cdeg;
    __syncthreads();
    float a = b3[t];
    for (int k = 0; k < H; ++k) a += pooled[k] * w3[k * H + t];
    t3[t] = a;
    __syncthreads();
    if (t < H / 2) {
        float m = l1b[t];
        for (int k = 0; k < H; ++k) m += t3[k] * l1w[k * (H / 2) + t];
        mid[t] = m;
    }
    __syncthreads();
    if (t < 3) {
        float o = l2b[t];
        for (int k = 0; k < H / 2; ++k) o += mid[k] * l2w[k * 3 + t];
        out[g * 3 + t] = o;
    }
}

extern "C" void kernel_launch(void* const* d_in, const int* in_sizes, int n_in,
                              void* d_out, int out_size, void* d_ws, size_t ws_size,
                              hipStream_t stream) {
    const float* x   = (const float*)d_in[0];
    const int*   ei  = (const int*)d_in[2];
    const int*   bat = (const int*)d_in[3];
    const float* w1  = (const float*)d_in[4];
    const float* b1  = (const float*)d_in[5];
    const float* w2  = (const float*)d_in[6];
    const float* b2  = (const float*)d_in[7];
    const float* w3  = (const float*)d_in[8];
    const float* b3  = (const float*)d_in[9];
    const float* l1w = (const float*)d_in[10];
    const float* l1b = (const float*)d_in[11];
    const float* l2w = (const float*)d_in[12];
    const float* l2b = (const float*)d_in[13];
    float* out = (float*)d_out;

    const int N = in_sizes[0] / 128;   // 50000
    const int E = in_sizes[2] / 2;     // 800000
    const int NB = (N + 255) / 256;

    char* ws = (char*)d_ws;
    size_t off = 0;
    auto alloc = [&](size_t bytes) {
        void* p = ws + off;
        off = (off + bytes + 255) & ~(size_t)255;
        return p;
    };
    // footprint ~68MB
    ushort* yb     = (ushort*)alloc((size_t)N * H * 2);   // bf16 ping (chunk-major)
    ushort* z16    = (ushort*)alloc((size_t)N * H * 2);   // bf16 pong (chunk-major)
    float*  cmat   = (float*)alloc((size_t)N * NG * 4);   // pool coefficients [N][64]
    int*    cnt    = (int*)alloc((size_t)N * 4);
    float*  dinv   = (float*)alloc((size_t)N * 4);
    int*    row_ptr= (int*)alloc((size_t)(N + 1) * 4);
    int*    fill   = (int*)alloc((size_t)N * 4);
    ushort* ssrc   = (ushort*)alloc((size_t)E * 2);
    int*    bsum   = (int*)alloc(256 * 4);
    int*    boff   = (int*)alloc(256 * 4);
    ushort* wt1h   = (ushort*)alloc((size_t)128 * 256 * 2);
    ushort* wt1l   = (ushort*)alloc((size_t)128 * 256 * 2);
    ushort* wt2h   = (ushort*)alloc((size_t)256 * 256 * 2);
    ushort* wt2l   = (ushort*)alloc((size_t)256 * 256 * 2);
    float*  sums   = (float*)alloc((size_t)NG * H * 4);

    hipMemsetAsync(cnt, 0, (size_t)N * 4, stream);

    hist_kernel<<<(E + 255) / 256, 256, 0, stream>>>(ei + E, cnt, E);
    scanA<<<NB, 256, 0, stream>>>(cnt, bsum, dinv, cmat, N);
    scanB<<<1, 256, 0, stream>>>(bsum, boff, row_ptr + N, NB, sums);
    scanC<<<NB, 256, 0, stream>>>(cnt, boff, row_ptr, fill, N);
    // fused: wconv + scatter + c-matrix + prescale
    int sp_blocks = (N * 32 + 255) / 256;
    wsp_kernel<<<WCONV_BLOCKS + sp_blocks, 256, 0, stream>>>(
        w1, wt1h, wt1l, w2, wt2h, wt2l,
        ei, ei + E, fill, ssrc, E, x, dinv, bat, cmat, yb, N);

    const int AGG_BLOCKS = (N + 31) / 32;
    // layer 1: chunked agg (4 chunks, width 128) -> MFMA GEMM 128->256
    agg_kernel<4><<<AGG_BLOCKS * 4, 256, 0, stream>>>(yb, dinv, row_ptr, ssrc, z16, N);
    mfma_gemm<true><<<dim3((N + 127) / 128, 4), 256, 0, stream>>>(z16, wt1h, wt1l, b1, dinv, yb, N, 128);

    // layer 2
    agg_kernel<8><<<AGG_BLOCKS * 8, 256, 0, stream>>>(yb, dinv, row_ptr, ssrc, z16, N);
    mfma_gemm<true><<<dim3((N + 127) / 128, 4), 256, 0, stream>>>(z16, wt2h, wt2l, b2, dinv, yb, N, 256);

    // layer 3 + pool: sums = c^T * y  (agg3 algebraically folded into pooling)
    pg_kernel<<<((N + 511) / 512) * 8, 256, 0, stream>>>(yb, cmat, sums, N);
    head_kernel<<<NG, 256, 0, stream>>>(sums, bat, N, w3, b3, l1w, l1b, l2w, l2b, out);
}